// Round 6
// baseline (186.779 us; speedup 1.0000x reference)
//
#include <hip/hip_runtime.h>
#include <stdint.h>

// ---------------------------------------------------------------------------
// SNN EMNIST forward: T=10, B=4096, IN=784, HID=256, NCLS=47
// R17: unlock the R16 overlap that the register allocator defeated.
// R16 PMC: VGPR_Count=100 (cap from __launch_bounds__(512,2)) proves the
// 17 frags (68 VGPR) could NOT stay live across the hash -> compiler sank
// the ds_reads below the hash, re-serializing hash vs MFMA (slab = 11K cyc
// = 5.5K hash + 5K serial gemm phase; VALUBusy 60% closes the arithmetic).
// LDS (116KB) already caps at 1 block/CU = 2 waves/SIMD, which the VGPR
// pool supports at up to 256 regs/wave -> raising the cap is free.
// Changes (scheduling only, dataflow identical):
//  1. __launch_bounds__(512, 1): frags stay live across hash.
//  2. Slab body = 5x { hash2 task s ; 12-MFMA chunk s } in PROGRAM ORDER
//     (robust overlap, independent of scheduler aggressiveness). MFMA
//     flatten (nt, plane, mt): same-acc MFMAs 5 apart; per-element order
//     still kw-asc x hi,mid,lo -> I_all bitwise identical.
//  3. Last slab peeled (no hash/stage/barrier).
// absmax stays 4.882812e-4. splitk/scanout unchanged for attribution.
// ---------------------------------------------------------------------------

#define T_STEPS 10
#define BATCH   4096
#define IN_DIM  784
#define HID     256
#define NCLS    47
#define NROWS   (T_STEPS * BATCH)        // 40960
#define KWORDS  25                       // ceil(784/32)
#define KPAD    800                      // 25*32
#define M_TILE  160

// d_ws layout (bytes):
//   [0, 41943040)          I_all  : float [40960][256]
//   [46039040, ...)        W1{hi,mid,lo}T : bf16 [256][800], 409600 B each
#define WS_IALL_OFF 0u
#define WS_W1HI_OFF 46039040u
#define WS_W1MD_OFF (46039040u + 409600u)
#define WS_W1LO_OFF (46039040u + 819200u)

typedef __attribute__((ext_vector_type(8))) short    bf16x8;
typedef __attribute__((ext_vector_type(4))) float    f32x4;
typedef __attribute__((ext_vector_type(4))) uint32_t u32x4;

__device__ __forceinline__ uint32_t rotl32(uint32_t x, uint32_t r) {
    return __builtin_amdgcn_alignbit(x, x, 32u - r);
}

// JAX threefry2x32, key=(0,42), partitionable scheme: out = o0^o1, x0=0, x1=i.
__device__ __forceinline__ uint32_t tf_hash(uint32_t lo) {
    const uint32_t ks1 = 42u;
    const uint32_t ks2 = 0x1BD11BDAu ^ 42u;
    uint32_t x0 = 0u;
    uint32_t x1 = lo + ks1;
#define TF_RND(r) { x0 += x1; x1 = rotl32(x1, r); x1 ^= x0; }
    TF_RND(13) TF_RND(15) TF_RND(26) TF_RND(6)
    x0 += ks1; x1 += ks2 + 1u;
    TF_RND(17) TF_RND(29) TF_RND(16) TF_RND(24)
    x0 += ks2; x1 += 2u;                       // ks0 == 0
    TF_RND(13) TF_RND(15) TF_RND(26) TF_RND(6)
    x1 += ks1 + 3u;                            // x0 += ks0 is a no-op
    TF_RND(17) TF_RND(29) TF_RND(16) TF_RND(24)
    x0 += ks1; x1 += ks2 + 4u;
    TF_RND(13) TF_RND(15) TF_RND(26) TF_RND(6)
    x0 += ks2; x1 += 5u;                       // ks0 == 0
#undef TF_RND
    return x0 ^ x1;
}

// Two consecutive spike bits -> one packed u32 (2 bf16 lanes). Identical
// compare expr / bf16 encoding to the verified path: even bit -> low bf16
// (0x3F80), odd bit -> high bf16 (0x3F800000).
__device__ __forceinline__ uint32_t hash2(uint32_t ib, const float* xp) {
    float2 xx = *(const float2*)xp;
    uint32_t w = 0u;
    w |= ((float)(tf_hash(ib + 0u) >> 9) < xx.x * 8388608.0f) ? 0x3F80u : 0u;
    w |= ((float)(tf_hash(ib + 1u) >> 9) < xx.y * 8388608.0f) ? 0x3F800000u : 0u;
    return w;
}

// ---------------------------------------------------------------------------
// Kernel B0: split W1 (f32 [784][256]) into transposed bf16 hi/mid/lo
// [256][800]. EXACT: hi+mid+lo == w bitwise.
// ---------------------------------------------------------------------------
__global__ __launch_bounds__(256) void splitk_k(
        const float* __restrict__ W1, ushort* __restrict__ hiT,
        ushort* __restrict__ midT, ushort* __restrict__ loT) {
    int n = blockIdx.x;                  // 0..255
    for (int k = threadIdx.x; k < KPAD; k += 256) {
        float w = (k < IN_DIM) ? W1[k * HID + n] : 0.0f;
        uint32_t u = __float_as_uint(w);
        uint32_t hb = (u + 0x7FFFu + ((u >> 16) & 1u)) >> 16;    // RNE to bf16
        float hf = __uint_as_float(hb << 16);
        float r1 = w - hf;                                       // exact
        uint32_t u1 = __float_as_uint(r1);
        uint32_t mb = (u1 + 0x7FFFu + ((u1 >> 16) & 1u)) >> 16;  // RNE
        float mf2 = __uint_as_float(mb << 16);
        float r2 = r1 - mf2;                                     // exact
        uint32_t u2 = __float_as_uint(r2);
        uint32_t lb = (u2 + 0x7FFFu + ((u2 >> 16) & 1u)) >> 16;  // exact fit
        hiT [n * KPAD + k] = (ushort)hb;
        midT[n * KPAD + k] = (ushort)mb;
        loT [n * KPAD + k] = (ushort)lb;
    }
}

// ---------------------------------------------------------------------------
// Fused spikegen + GEMM: I_all = bernoulli(x) @ W1 + b1 (3-plane exact bf16).
// Block: 160 rows x 256 cols, 512 threads = 8 waves (2M x 4N), wave = 80x64
// = 5x4 tiles of 16x16x32. Grid 256 = 1 block/CU. A and B double-buffered;
// one __syncthreads per slab. Slab body: issue B[kw+1] global_load_lds ->
// ds_read ALL 17 cur frags -> 5x { hash2 task -> 12 MFMA } -> barrier, flip.
// LDS: A bufs [0,20480), B bufs 20480 + c*49152 {hi+0, mid+16384, lo+32768}.
// ---------------------------------------------------------------------------
#define LDS_B0  20480
#define B_BUFSZ 49152
#define A_BUFSZ 10240

__global__ __launch_bounds__(512, 1) void fused_gemm_k(
        const ushort* __restrict__ hiT, const ushort* __restrict__ midT,
        const ushort* __restrict__ loT, const float* __restrict__ b1,
        const float* __restrict__ x, float* __restrict__ I_all) {
    __shared__ __align__(16) char lds[118784];   // 116 KB, 1 block/CU

    const int tid = threadIdx.x;
    const int l   = tid & 63;
    const int wv  = tid >> 6;        // 0..7
    const int wm  = wv >> 2;         // 0..1 (M half)
    const int wn  = wv & 3;          // 0..3 (N quarter)
    const int m0  = blockIdx.x * M_TILE;

    f32x4 acc[5][4] = {};

    // fragment read addressing (shared swizzle sig for A and B)
    const int q   = l >> 4;
    const int sig = q ^ (l & 3) ^ ((l >> 2) & 3);
    const int a_rd = wm * 5120 + ((l & 15) << 6) + (sig << 4);      // in A buf
    const int b_rd = (((wn << 6) + (l & 15)) << 6) + (sig << 4);    // in plane

    // ---- B staging: 1024 slots of 16B per plane, 2 per thread ----
    const ushort* hi_p[2];
    const ushort* md_p[2];
    const ushort* lo_p[2];
    int bdst[2];
#pragma unroll
    for (int i = 0; i < 2; ++i) {
        int s  = (i << 9) + tid;
        int n  = s >> 2;
        int qs = s & 3;
        int qd = qs ^ (n & 3) ^ ((n >> 2) & 3);
        size_t eoff = (size_t)n * KPAD + ((size_t)qd << 3);
        hi_p[i] = hiT  + eoff;
        md_p[i] = midT + eoff;
        lo_p[i] = loT  + eoff;
        bdst[i] = ((i << 9) + (wv << 6)) << 4;    // wave-uniform base
    }

    // ---- A expansion: 2560 hash2 tasks/slab = exactly 5 per thread. ----
    // Task tau = tid + 512*s: row = tau>>4 (0..159), pair p = tau&15;
    // computes bits {2p, 2p+1} of (row, slab)'s 32-bit word -> one u32
    // (2 bf16) at frag dword: quarter qd = (p>>2)^swz(row), dword p&3.
    int      adst[5];
    const float* txp[5];
    uint32_t tib[5];
    int      tpp[5];
#pragma unroll
    for (int s = 0; s < 5; ++s) {
        int tau = tid + (s << 9);
        int row = tau >> 4;
        int p   = tau & 15;
        int qd  = (p >> 2) ^ (row & 3) ^ ((row >> 2) & 3);
        adst[s] = (row << 6) + (qd << 4) + ((p & 3) << 2);
        int rowg = m0 + row;
        txp[s]  = x + (size_t)(rowg & (BATCH - 1)) * IN_DIM + (p << 1);
        tib[s]  = (uint32_t)rowg * (uint32_t)IN_DIM + (uint32_t)(p << 1);
        tpp[s]  = p;
    }

#define STAGE_B(koff, bbase) \
    _Pragma("unroll") \
    for (int i = 0; i < 2; ++i) { \
        __builtin_amdgcn_global_load_lds( \
            (const __attribute__((address_space(1))) void*)(hi_p[i] + (koff)), \
            (__attribute__((address_space(3))) void*)(lds + (bbase) + bdst[i]), \
            16, 0, 0); \
        __builtin_amdgcn_global_load_lds( \
            (const __attribute__((address_space(1))) void*)(md_p[i] + (koff)), \
            (__attribute__((address_space(3))) void*)(lds + (bbase) + 16384 + bdst[i]), \
            16, 0, 0); \
        __builtin_amdgcn_global_load_lds( \
            (const __attribute__((address_space(1))) void*)(lo_p[i] + (koff)), \
            (__attribute__((address_space(3))) void*)(lds + (bbase) + 32768 + bdst[i]), \
            16, 0, 0); \
    }

// one hash2 task: bits {2p,2p+1} of next slab -> u32 -> ds_write_b32.
// is_tail (slab 24): pairs p>=8 (k>=784) stay zero (also guards x OOB).
#define HASH_TASK(s, koff, abase, is_tail) { \
    uint32_t w_ = 0u; \
    if (!(is_tail) || tpp[s] < 8) \
        w_ = hash2(tib[s] + (uint32_t)(koff), txp[s] + (koff)); \
    *(uint32_t*)(lds + (abase) + adst[s]) = w_; }

// 12 MFMAs, flat index m = (s)*12..+11; (nt, plane, mt) order: nt = m/15,
// plane = (m%15)/5, mt = m%5. Per acc element still hi->mid->lo, kw asc.
#define MFMA_CHUNK(s) \
    _Pragma("unroll") \
    for (int m = (s) * 12; m < (s) * 12 + 12; ++m) { \
        const int nt_ = m / 15, r_ = m % 15, pl_ = r_ / 5, mt_ = r_ % 5; \
        acc[mt_][nt_] = __builtin_amdgcn_mfma_f32_16x16x32_bf16( \
            af[mt_], bfr[pl_][nt_], acc[mt_][nt_], 0, 0, 0); \
    }

#define PRELOAD_FRAGS(bufidx) \
    const char* A = lds + (bufidx) * A_BUFSZ; \
    const char* B = lds + LDS_B0 + (bufidx) * B_BUFSZ; \
    bf16x8 af[5]; \
    bf16x8 bfr[3][4]; \
    _Pragma("unroll") \
    for (int mt = 0; mt < 5; ++mt) \
        af[mt] = *(const bf16x8*)(A + a_rd + (mt << 10)); \
    _Pragma("unroll") \
    for (int nt = 0; nt < 4; ++nt) { \
        bfr[0][nt] = *(const bf16x8*)(B + b_rd + (nt << 10)); \
        bfr[1][nt] = *(const bf16x8*)(B + 16384 + b_rd + (nt << 10)); \
        bfr[2][nt] = *(const bf16x8*)(B + 32768 + b_rd + (nt << 10)); \
    }

    // ---- prologue: stage + hash slab 0 into buffers 0 ----
    STAGE_B(0, LDS_B0)
    HASH_TASK(0, 0, 0, false)
    HASH_TASK(1, 0, 0, false)
    HASH_TASK(2, 0, 0, false)
    HASH_TASK(3, 0, 0, false)
    HASH_TASK(4, 0, 0, false)
    __syncthreads();

    int cur = 0;
#pragma unroll 1
    for (int kw = 0; kw < KWORDS - 1; ++kw) {
        const int  nxt  = cur ^ 1;
        const int  koff = (kw + 1) << 5;              // +32 elems per slab
        const bool tail = (kw == KWORDS - 2);         // hashing slab 24

        // (1) issue next slab's B loads first (vmcnt queue fills early)
        STAGE_B(koff, LDS_B0 + nxt * B_BUFSZ)

        // (2) preload ALL 17 cur frags (lgkm latency hides under task 0)
        PRELOAD_FRAGS(cur)

        // (3) program-order interleave: hash task s ; 12-MFMA chunk s
        const int ab = nxt * A_BUFSZ;
        HASH_TASK(0, koff, ab, tail)  MFMA_CHUNK(0)
        HASH_TASK(1, koff, ab, tail)  MFMA_CHUNK(1)
        HASH_TASK(2, koff, ab, tail)  MFMA_CHUNK(2)
        HASH_TASK(3, koff, ab, tail)  MFMA_CHUNK(3)
        HASH_TASK(4, koff, ab, tail)  MFMA_CHUNK(4)

        __syncthreads();   // drains vmcnt (B nxt) + lgkm (A nxt); flip safe
        cur = nxt;
    }

    {   // ---- last slab (kw=24): no hash, no stage, no trailing barrier ----
        PRELOAD_FRAGS(cur)
        MFMA_CHUNK(0) MFMA_CHUNK(1) MFMA_CHUNK(2) MFMA_CHUNK(3) MFMA_CHUNK(4)
    }
#undef STAGE_B
#undef HASH_TASK
#undef MFMA_CHUNK
#undef PRELOAD_FRAGS

    // --- epilogue: acc -> I_all (+ b1) ---
    const int c0 = l & 15;
    float b1v[4];
#pragma unroll
    for (int nt = 0; nt < 4; ++nt)
        b1v[nt] = b1[(wn << 6) + (nt << 4) + c0];
#pragma unroll
    for (int mt = 0; mt < 5; ++mt) {
#pragma unroll
        for (int nt = 0; nt < 4; ++nt) {
            int col = (wn << 6) + (nt << 4) + c0;
#pragma unroll
            for (int r = 0; r < 4; ++r) {
                int row = m0 + wm * 80 + (mt << 4) + (q << 2) + r;
                I_all[(size_t)row * HID + col] = acc[mt][nt][r] + b1v[nt];
            }
        }
    }
}

// ---------------------------------------------------------------------------
// Fused LIF scan + readout: per block, 4 batch rows (1024 blocks = 4/CU).
// Phase 1: thread h scans 4 rows over t (exact reference op order) -> g in
// LDS. Phase 2: wave wv -> row b0+wv, lane c<47: out = sum_h g[b][h]*Wr[h][c]
// (+ br*(1-2^-10)), h ascending — identical fmaf chain to R16.
// ---------------------------------------------------------------------------
__global__ __launch_bounds__(256) void scanout_k(
        const float* __restrict__ I_all, const float* __restrict__ Wr,
        const float* __restrict__ br, float* __restrict__ out) {
    __shared__ float gl[4 * 256];        // 4 KB
    const int tid = threadIdx.x;
    const int b0  = blockIdx.x << 2;

#pragma unroll
    for (int b = 0; b < 4; ++b) {
        const float* p = I_all + ((size_t)(b0 + b) << 8) + tid;
        float v = 0.f, ga = 0.f, wt = 0.0009765625f;   // 2^-10
#pragma unroll
        for (int t = 0; t < T_STEPS; ++t) {
            float I = p[(size_t)t * BATCH * HID];
            v = v + (I - v) * 0.5f;
            if (v >= 1.0f) { ga += wt; v = 0.f; }
            wt += wt;
        }
        gl[(b << 8) + tid] = ga;
    }
    __syncthreads();

    const int wv = tid >> 6;             // wave -> batch row b0+wv
    const int c  = tid & 63;
    if (c >= NCLS) return;
    const float* gb = &gl[wv << 8];
    float acc = 0.f;
    for (int h4 = 0; h4 < 64; ++h4) {
        float w0 = Wr[((h4 << 2) + 0) * NCLS + c];
        float w1 = Wr[((h4 << 2) + 1) * NCLS + c];
        float w2 = Wr[((h4 << 2) + 2) * NCLS + c];
        float w3 = Wr[((h4 << 2) + 3) * NCLS + c];
        float4 gg = *(const float4*)&gb[h4 << 2];
        acc = fmaf(gg.x, w0, acc);
        acc = fmaf(gg.y, w1, acc);
        acc = fmaf(gg.z, w2, acc);
        acc = fmaf(gg.w, w3, acc);
    }
    float brv = br[c] * 0.9990234375f;
    out[(b0 + wv) * NCLS + c] = acc + brv;
}

extern "C" void kernel_launch(void* const* d_in, const int* in_sizes, int n_in,
                              void* d_out, int out_size, void* d_ws, size_t ws_size,
                              hipStream_t stream) {
    const float* x  = (const float*)d_in[0];
    const float* W1 = (const float*)d_in[1];
    const float* b1 = (const float*)d_in[2];
    const float* Wr = (const float*)d_in[3];
    const float* br = (const float*)d_in[4];
    float* out = (float*)d_out;

    float*  I_all = (float*) ((char*)d_ws + WS_IALL_OFF);
    ushort* w1hi  = (ushort*)((char*)d_ws + WS_W1HI_OFF);
    ushort* w1md  = (ushort*)((char*)d_ws + WS_W1MD_OFF);
    ushort* w1lo  = (ushort*)((char*)d_ws + WS_W1LO_OFF);

    splitk_k<<<HID, 256, 0, stream>>>(W1, w1hi, w1md, w1lo);
    fused_gemm_k<<<NROWS / M_TILE, 512, 0, stream>>>(w1hi, w1md, w1lo, b1, x, I_all);
    scanout_k<<<BATCH / 4, 256, 0, stream>>>(I_all, Wr, br, out);
}

// Round 7
// 171.760 us; speedup vs baseline: 1.0874x; 1.0874x over previous
//
#include <hip/hip_runtime.h>
#include <stdint.h>

// ---------------------------------------------------------------------------
// SNN EMNIST forward: T=10, B=4096, IN=784, HID=256, NCLS=47
// R18: KILL I_all. R17 accounting: gemm 115.5us + scanout ~60us (inferred,
// vs ~10us roofline for its 42MB) + splitk ~3 + gaps. I_all is written
// (41MB) then immediately re-read (41MB) -> pure waste.
// Change: remap gemm tile rows to r = t*16 + j (g = t*4096 + b0 + j), so one
// block owns ALL 10 timesteps of 16 batch rows. K-loop byte-identical (only
// the hash row->(t,b) map changes; per-row compute unchanged -> I bitwise
// identical). Epilogue: wm=0 waves park t=0..4 I-vals in dead LDS; wm=1
// threads run the EXACT LIF scan (t0..4 from LDS, t5..9 from own regs, same
// op order as scanout_k) -> g in LDS; 8 waves do the identical ascending-h
// fmaf readout -> out. scanout_k deleted. x read drops 10x per block.
// absmax stays 4.882812e-4. splitk unchanged.
// ---------------------------------------------------------------------------

#define T_STEPS 10
#define BATCH   4096
#define IN_DIM  784
#define HID     256
#define NCLS    47
#define NROWS   (T_STEPS * BATCH)        // 40960
#define KWORDS  25                       // ceil(784/32)
#define KPAD    800                      // 25*32
#define M_TILE  160

// d_ws layout (bytes):
//   [46039040, ...)        W1{hi,mid,lo}T : bf16 [256][800], 409600 B each
#define WS_W1HI_OFF 46039040u
#define WS_W1MD_OFF (46039040u + 409600u)
#define WS_W1LO_OFF (46039040u + 819200u)

typedef __attribute__((ext_vector_type(8))) short    bf16x8;
typedef __attribute__((ext_vector_type(4))) float    f32x4;
typedef __attribute__((ext_vector_type(4))) uint32_t u32x4;

__device__ __forceinline__ uint32_t rotl32(uint32_t x, uint32_t r) {
    return __builtin_amdgcn_alignbit(x, x, 32u - r);
}

// JAX threefry2x32, key=(0,42), partitionable scheme: out = o0^o1, x0=0, x1=i.
__device__ __forceinline__ uint32_t tf_hash(uint32_t lo) {
    const uint32_t ks1 = 42u;
    const uint32_t ks2 = 0x1BD11BDAu ^ 42u;
    uint32_t x0 = 0u;
    uint32_t x1 = lo + ks1;
#define TF_RND(r) { x0 += x1; x1 = rotl32(x1, r); x1 ^= x0; }
    TF_RND(13) TF_RND(15) TF_RND(26) TF_RND(6)
    x0 += ks1; x1 += ks2 + 1u;
    TF_RND(17) TF_RND(29) TF_RND(16) TF_RND(24)
    x0 += ks2; x1 += 2u;                       // ks0 == 0
    TF_RND(13) TF_RND(15) TF_RND(26) TF_RND(6)
    x1 += ks1 + 3u;                            // x0 += ks0 is a no-op
    TF_RND(17) TF_RND(29) TF_RND(16) TF_RND(24)
    x0 += ks1; x1 += ks2 + 4u;
    TF_RND(13) TF_RND(15) TF_RND(26) TF_RND(6)
    x0 += ks2; x1 += 5u;                       // ks0 == 0
#undef TF_RND
    return x0 ^ x1;
}

// Two consecutive spike bits -> one packed u32 (2 bf16 lanes). Identical
// compare expr / bf16 encoding to the verified path.
__device__ __forceinline__ uint32_t hash2(uint32_t ib, const float* xp) {
    float2 xx = *(const float2*)xp;
    uint32_t w = 0u;
    w |= ((float)(tf_hash(ib + 0u) >> 9) < xx.x * 8388608.0f) ? 0x3F80u : 0u;
    w |= ((float)(tf_hash(ib + 1u) >> 9) < xx.y * 8388608.0f) ? 0x3F800000u : 0u;
    return w;
}

// ---------------------------------------------------------------------------
// Kernel B0: split W1 (f32 [784][256]) into transposed bf16 hi/mid/lo
// [256][800]. EXACT: hi+mid+lo == w bitwise.
// ---------------------------------------------------------------------------
__global__ __launch_bounds__(256) void splitk_k(
        const float* __restrict__ W1, ushort* __restrict__ hiT,
        ushort* __restrict__ midT, ushort* __restrict__ loT) {
    int n = blockIdx.x;                  // 0..255
    for (int k = threadIdx.x; k < KPAD; k += 256) {
        float w = (k < IN_DIM) ? W1[k * HID + n] : 0.0f;
        uint32_t u = __float_as_uint(w);
        uint32_t hb = (u + 0x7FFFu + ((u >> 16) & 1u)) >> 16;    // RNE to bf16
        float hf = __uint_as_float(hb << 16);
        float r1 = w - hf;                                       // exact
        uint32_t u1 = __float_as_uint(r1);
        uint32_t mb = (u1 + 0x7FFFu + ((u1 >> 16) & 1u)) >> 16;  // RNE
        float mf2 = __uint_as_float(mb << 16);
        float r2 = r1 - mf2;                                     // exact
        uint32_t u2 = __float_as_uint(r2);
        uint32_t lb = (u2 + 0x7FFFu + ((u2 >> 16) & 1u)) >> 16;  // exact fit
        hiT [n * KPAD + k] = (ushort)hb;
        midT[n * KPAD + k] = (ushort)mb;
        loT [n * KPAD + k] = (ushort)lb;
    }
}

// ---------------------------------------------------------------------------
// Fused spikegen + GEMM + LIF scan + readout.
// Block: 16 batch rows x 10 timesteps = 160 tile rows x 256 cols, 512
// threads = 8 waves (2M x 4N), wave = 80x64 = 5x4 tiles of 16x16x32.
// Tile row r = t*16 + j: t = r>>4, b = b0 + (r&15). Grid 256 = 1 block/CU.
// K-loop identical to R17 (dbuf A+B, 1 barrier/slab, 5x{hash2;12 MFMA}).
// Epilogue (replaces I_all store + scanout kernel):
//   wave wm half -> t = wm*5 + mt, j = q*4 + rr, col = wn*64 + nt*16 + c0.
//   P1: wm=0 stores I(t=0..4) = acc+b1 to LDS i0[80][258] (pad: no bank dup)
//   P2: wm=1 scans (j,col): t0..4 from i0, t5..9 from own acc+b1 -- exact
//       scanout op order -> g[16][260] in LDS
//   P3: 8 waves x 2 rows: identical ascending-h fmaf readout -> out.
// ---------------------------------------------------------------------------
#define LDS_B0  20480
#define B_BUFSZ 49152
#define A_BUFSZ 10240
#define I0_LDW  258                      // i0 row pitch (floats), breaks 4-way
#define G_LDW   260                      // g row pitch (floats), 16B-aligned
#define G_OFF   83200                    // after i0: 80*258*4 = 82560, pad up

__global__ __launch_bounds__(512, 1) void fused_gemm_k(
        const ushort* __restrict__ hiT, const ushort* __restrict__ midT,
        const ushort* __restrict__ loT, const float* __restrict__ b1,
        const float* __restrict__ x, const float* __restrict__ Wr,
        const float* __restrict__ br, float* __restrict__ out) {
    __shared__ __align__(16) char lds[118784];   // 116 KB, 1 block/CU

    const int tid = threadIdx.x;
    const int l   = tid & 63;
    const int wv  = tid >> 6;        // 0..7
    const int wm  = wv >> 2;         // 0..1 (M half: t 0-4 vs 5-9)
    const int wn  = wv & 3;          // 0..3 (N quarter)
    const int b0  = blockIdx.x << 4; // 16 batch rows per block

    f32x4 acc[5][4] = {};

    // fragment read addressing (shared swizzle sig for A and B)
    const int q   = l >> 4;
    const int sig = q ^ (l & 3) ^ ((l >> 2) & 3);
    const int a_rd = wm * 5120 + ((l & 15) << 6) + (sig << 4);      // in A buf
    const int b_rd = (((wn << 6) + (l & 15)) << 6) + (sig << 4);    // in plane

    // ---- B staging: 1024 slots of 16B per plane, 2 per thread ----
    const ushort* hi_p[2];
    const ushort* md_p[2];
    const ushort* lo_p[2];
    int bdst[2];
#pragma unroll
    for (int i = 0; i < 2; ++i) {
        int s  = (i << 9) + tid;
        int n  = s >> 2;
        int qs = s & 3;
        int qd = qs ^ (n & 3) ^ ((n >> 2) & 3);
        size_t eoff = (size_t)n * KPAD + ((size_t)qd << 3);
        hi_p[i] = hiT  + eoff;
        md_p[i] = midT + eoff;
        lo_p[i] = loT  + eoff;
        bdst[i] = ((i << 9) + (wv << 6)) << 4;    // wave-uniform base
    }

    // ---- A expansion: 2560 hash2 tasks/slab = exactly 5 per thread. ----
    // Task tau = tid + 512*s: tile row = tau>>4 (0..159), pair p = tau&15.
    // Global row g = (row>>4)*4096 + b0 + (row&15)  [r = t*16 + j mapping].
    int      adst[5];
    const float* txp[5];
    uint32_t tib[5];
    int      tpp[5];
#pragma unroll
    for (int s = 0; s < 5; ++s) {
        int tau = tid + (s << 9);
        int row = tau >> 4;
        int p   = tau & 15;
        int qd  = (p >> 2) ^ (row & 3) ^ ((row >> 2) & 3);
        adst[s] = (row << 6) + (qd << 4) + ((p & 3) << 2);
        int rowg = ((row >> 4) * BATCH) + b0 + (row & 15);
        txp[s]  = x + (size_t)(b0 + (row & 15)) * IN_DIM + (p << 1);
        tib[s]  = (uint32_t)rowg * (uint32_t)IN_DIM + (uint32_t)(p << 1);
        tpp[s]  = p;
    }

#define STAGE_B(koff, bbase) \
    _Pragma("unroll") \
    for (int i = 0; i < 2; ++i) { \
        __builtin_amdgcn_global_load_lds( \
            (const __attribute__((address_space(1))) void*)(hi_p[i] + (koff)), \
            (__attribute__((address_space(3))) void*)(lds + (bbase) + bdst[i]), \
            16, 0, 0); \
        __builtin_amdgcn_global_load_lds( \
            (const __attribute__((address_space(1))) void*)(md_p[i] + (koff)), \
            (__attribute__((address_space(3))) void*)(lds + (bbase) + 16384 + bdst[i]), \
            16, 0, 0); \
        __builtin_amdgcn_global_load_lds( \
            (const __attribute__((address_space(1))) void*)(lo_p[i] + (koff)), \
            (__attribute__((address_space(3))) void*)(lds + (bbase) + 32768 + bdst[i]), \
            16, 0, 0); \
    }

#define HASH_TASK(s, koff, abase, is_tail) { \
    uint32_t w_ = 0u; \
    if (!(is_tail) || tpp[s] < 8) \
        w_ = hash2(tib[s] + (uint32_t)(koff), txp[s] + (koff)); \
    *(uint32_t*)(lds + (abase) + adst[s]) = w_; }

#define MFMA_CHUNK(s) \
    _Pragma("unroll") \
    for (int m = (s) * 12; m < (s) * 12 + 12; ++m) { \
        const int nt_ = m / 15, r_ = m % 15, pl_ = r_ / 5, mt_ = r_ % 5; \
        acc[mt_][nt_] = __builtin_amdgcn_mfma_f32_16x16x32_bf16( \
            af[mt_], bfr[pl_][nt_], acc[mt_][nt_], 0, 0, 0); \
    }

#define PRELOAD_FRAGS(bufidx) \
    const char* A = lds + (bufidx) * A_BUFSZ; \
    const char* B = lds + LDS_B0 + (bufidx) * B_BUFSZ; \
    bf16x8 af[5]; \
    bf16x8 bfr[3][4]; \
    _Pragma("unroll") \
    for (int mt = 0; mt < 5; ++mt) \
        af[mt] = *(const bf16x8*)(A + a_rd + (mt << 10)); \
    _Pragma("unroll") \
    for (int nt = 0; nt < 4; ++nt) { \
        bfr[0][nt] = *(const bf16x8*)(B + b_rd + (nt << 10)); \
        bfr[1][nt] = *(const bf16x8*)(B + 16384 + b_rd + (nt << 10)); \
        bfr[2][nt] = *(const bf16x8*)(B + 32768 + b_rd + (nt << 10)); \
    }

    // ---- prologue: stage + hash slab 0 into buffers 0 ----
    STAGE_B(0, LDS_B0)
    HASH_TASK(0, 0, 0, false)
    HASH_TASK(1, 0, 0, false)
    HASH_TASK(2, 0, 0, false)
    HASH_TASK(3, 0, 0, false)
    HASH_TASK(4, 0, 0, false)
    __syncthreads();

    int cur = 0;
#pragma unroll 1
    for (int kw = 0; kw < KWORDS - 1; ++kw) {
        const int  nxt  = cur ^ 1;
        const int  koff = (kw + 1) << 5;              // +32 elems per slab
        const bool tail = (kw == KWORDS - 2);         // hashing slab 24

        STAGE_B(koff, LDS_B0 + nxt * B_BUFSZ)
        PRELOAD_FRAGS(cur)

        const int ab = nxt * A_BUFSZ;
        HASH_TASK(0, koff, ab, tail)  MFMA_CHUNK(0)
        HASH_TASK(1, koff, ab, tail)  MFMA_CHUNK(1)
        HASH_TASK(2, koff, ab, tail)  MFMA_CHUNK(2)
        HASH_TASK(3, koff, ab, tail)  MFMA_CHUNK(3)
        HASH_TASK(4, koff, ab, tail)  MFMA_CHUNK(4)

        __syncthreads();   // drains vmcnt (B nxt) + lgkm (A nxt); flip safe
        cur = nxt;
    }

    {   // ---- last slab (kw=24): no hash, no stage ----
        PRELOAD_FRAGS(cur)
        MFMA_CHUNK(0) MFMA_CHUNK(1) MFMA_CHUNK(2) MFMA_CHUNK(3) MFMA_CHUNK(4)
    }
#undef STAGE_B
#undef HASH_TASK
#undef MFMA_CHUNK
#undef PRELOAD_FRAGS

    // =======================================================================
    // Epilogue: in-block LIF scan + readout (I_all never leaves the CU).
    // Thread's acc[mt][nt][rr] = I(t = wm*5+mt, j = q*4+rr, col).
    // =======================================================================
    const int c0 = l & 15;
    float b1v[4];
#pragma unroll
    for (int nt = 0; nt < 4; ++nt)
        b1v[nt] = b1[(wn << 6) + (nt << 4) + c0];

    __syncthreads();                       // K-loop LDS dead; reuse
    float* i0   = (float*)lds;             // [80][I0_LDW]: (t0..4 x j) x col
    float* gbuf = (float*)(lds + G_OFF);   // [16][G_LDW]

    if (wm == 0) {                         // park I(t=0..4)
#pragma unroll
        for (int mt = 0; mt < 5; ++mt)
#pragma unroll
            for (int nt = 0; nt < 4; ++nt) {
                int col = (wn << 6) + (nt << 4) + c0;
#pragma unroll
                for (int r = 0; r < 4; ++r) {
                    int j = (q << 2) + r;
                    i0[(mt * 16 + j) * I0_LDW + col] = acc[mt][nt][r] + b1v[nt];
                }
            }
    }
    __syncthreads();

    if (wm == 1) {                         // scan: exact scanout_k op order
#pragma unroll
        for (int nt = 0; nt < 4; ++nt) {
            int col = (wn << 6) + (nt << 4) + c0;
#pragma unroll
            for (int r = 0; r < 4; ++r) {
                int j = (q << 2) + r;
                float v = 0.f, ga = 0.f, wt = 0.0009765625f;   // 2^-10
#pragma unroll
                for (int t = 0; t < 5; ++t) {
                    float I = i0[(t * 16 + j) * I0_LDW + col];
                    v = v + (I - v) * 0.5f;
                    if (v >= 1.0f) { ga += wt; v = 0.f; }
                    wt += wt;
                }
#pragma unroll
                for (int mt = 0; mt < 5; ++mt) {               // t = 5 + mt
                    float I = acc[mt][nt][r] + b1v[nt];
                    v = v + (I - v) * 0.5f;
                    if (v >= 1.0f) { ga += wt; v = 0.f; }
                    wt += wt;
                }
                gbuf[j * G_LDW + col] = ga;
            }
        }
    }
    __syncthreads();

    {   // readout: wave wv -> rows 2wv, 2wv+1; identical fmaf chain
        const int c = l;
        if (c < NCLS) {
            float brv = br[c] * 0.9990234375f;
#pragma unroll
            for (int rr = 0; rr < 2; ++rr) {
                int j = (wv << 1) + rr;
                const float* gb = &gbuf[j * G_LDW];
                float a = 0.f;
                for (int h4 = 0; h4 < 64; ++h4) {
                    float w0 = Wr[((h4 << 2) + 0) * NCLS + c];
                    float w1 = Wr[((h4 << 2) + 1) * NCLS + c];
                    float w2 = Wr[((h4 << 2) + 2) * NCLS + c];
                    float w3 = Wr[((h4 << 2) + 3) * NCLS + c];
                    float4 gg = *(const float4*)&gb[h4 << 2];
                    a = fmaf(gg.x, w0, a);
                    a = fmaf(gg.y, w1, a);
                    a = fmaf(gg.z, w2, a);
                    a = fmaf(gg.w, w3, a);
                }
                out[(b0 + j) * NCLS + c] = a + brv;
            }
        }
    }
}

extern "C" void kernel_launch(void* const* d_in, const int* in_sizes, int n_in,
                              void* d_out, int out_size, void* d_ws, size_t ws_size,
                              hipStream_t stream) {
    const float* x  = (const float*)d_in[0];
    const float* W1 = (const float*)d_in[1];
    const float* b1 = (const float*)d_in[2];
    const float* Wr = (const float*)d_in[3];
    const float* br = (const float*)d_in[4];
    float* out = (float*)d_out;

    ushort* w1hi  = (ushort*)((char*)d_ws + WS_W1HI_OFF);
    ushort* w1md  = (ushort*)((char*)d_ws + WS_W1MD_OFF);
    ushort* w1lo  = (ushort*)((char*)d_ws + WS_W1LO_OFF);

    splitk_k<<<HID, 256, 0, stream>>>(W1, w1hi, w1md, w1lo);
    fused_gemm_k<<<BATCH / 16, 512, 0, stream>>>(w1hi, w1md, w1lo, b1, x,
                                                 Wr, br, out);
}